// Round 3
// baseline (165.319 us; speedup 1.0000x reference)
//
#include <hip/hip_runtime.h>
#include <hip/hip_bf16.h>

// Radon transform: x (4,1,384,384) f32 -> out (4,460,64) f32
// pad = 38, Hp = Wp = 460, N_ANGLES = 64.
//
// R3 structure: one wave = one (b,a) x 64 consecutive y (lane = y), each lane
// accumulates its own output in-register -> NO cross-lane reduce. 4 waves per
// block split the xx-range into 4 chunks (occupancy), combined via 1KB LDS.
// Per-lane xx-interval clip (rcp-based, conservative +/-2, absorbed by the
// 6px zero border). Normal + transposed staged images; per angle we sample the
// layout whose memory-row spread across lanes is smaller (<= 63/sqrt(2)).

constexpr int IMG = 384;
constexpr int PAD = 38;
constexpr int P   = 460;   // Hp = Wp
constexpr int NA  = 64;
constexpr int NB  = 4;
constexpr int B_  = 6;               // zero border
constexpr int O_  = PAD - B_;        // 32
constexpr int E_  = IMG + 2 * B_;    // 396
constexpr int NCHUNK = 4;
constexpr int CHUNK  = P / NCHUNK;   // 115

__global__ __launch_bounds__(256) void pad2_kernel(const float* __restrict__ x,
                                                   float* __restrict__ pb,
                                                   float* __restrict__ pbT) {
    int idx = blockIdx.x * 256 + threadIdx.x;
    if (idx >= NB * E_ * E_) return;
    int b  = idx / (E_ * E_);
    int r  = idx - b * (E_ * E_);
    int iy = r / E_;
    int ix = r - iy * E_;
    int py = iy + O_ - PAD;
    int px = ix + O_ - PAD;
    float v = ((unsigned)py < (unsigned)IMG && (unsigned)px < (unsigned)IMG)
                  ? x[(b * IMG + py) * IMG + px] : 0.0f;
    pb[idx] = v;
    pbT[(b * E_ + ix) * E_ + iy] = v;
}

__global__ __launch_bounds__(256) void radon_kernel(const float* __restrict__ pb,
                                                    const float* __restrict__ pbT,
                                                    float* __restrict__ out) {
    const int lane = threadIdx.x & 63;
    const int wv   = threadIdx.x >> 6;       // xx-chunk id
    const int a    = blockIdx.y;
    const int b    = blockIdx.z;
    const int y    = blockIdx.x * 64 + lane;

    const float th = (2.8125f * (float)a) * 0.017453292519943295f;
    float s, c;
    __sincosf(th, &s, &c);

    const float yf = (float)(y < P ? y : P - 1);
    const float ys = (2.0f * yf + 1.0f) / 460.0f - 1.0f;
    // fix = c*xx + A ; fiy = s*xx + By (padded-image pixel coords)
    const float A  = fmaf(-s, ys, 1.0f) * 230.0f - 0.5f - 229.5f * c;
    const float By = fmaf( c, ys, 1.0f) * 230.0f - 0.5f - 229.5f * s;

    // xx-interval where the stencil can touch the core ([36,424] conservative,
    // rcp error + floor slack covered by +/-2 and the 6px border).
    // inf/NaN endpoints (exact s=0 at a=0) resolve to correctly-empty/full
    // intervals under v_min/v_max minNum semantics.
    const float rc = __builtin_amdgcn_rcpf(c);
    const float rs = __builtin_amdgcn_rcpf(s);
    float t0 = (36.0f - A) * rc, t1 = (424.0f - A) * rc;
    float lo = fmaxf(0.0f,   fminf(t0, t1));
    float hi = fminf(459.0f, fmaxf(t0, t1));
    t0 = (36.0f - By) * rs; t1 = (424.0f - By) * rs;
    lo = fmaxf(lo, fminf(t0, t1));
    hi = fminf(hi, fmaxf(t0, t1));

    int xlo = max(wv * CHUNK,             (int)floorf(lo) - 2);
    int xhi = min(wv * CHUNK + CHUNK - 1, (int)ceilf(hi) + 2);
    if (y >= P) { xlo = 1; xhi = 0; }

    // Pick layout with smaller lane->row spread: rows step by |c| (normal)
    // or |s| (transposed). Bilinear is symmetric under the (u,v) swap, so the
    // sampled values are identical.
    const bool  useT = fabsf(c) > fabsf(s);
    const float cu = useT ? s  : c;
    const float Au = useT ? By : A;
    const float cv = useT ? c  : s;
    const float Av = useT ? A  : By;
    const float* __restrict__ base = (useT ? pbT : pb) + b * E_ * E_;

    float acc = 0.0f;
    for (int xx = xlo; xx <= xhi; ++xx) {
        const float xxf = (float)xx;
        const float u   = fmaf(cu, xxf, Au);
        const float v   = fmaf(cv, xxf, Av);
        const float u0f = floorf(u);
        const float v0f = floorf(v);
        const float wu  = u - u0f;
        const float wvv = v - v0f;
        const int idx = (int)fmaf(v0f, (float)E_, u0f) - (O_ * E_ + O_);
        const float* p = base + idx;
        const float p00 = p[0];
        const float p01 = p[1];
        const float p10 = p[E_];
        const float p11 = p[E_ + 1];
        const float top = fmaf(wu, p01 - p00, p00);
        const float bot = fmaf(wu, p11 - p10, p10);
        acc += fmaf(wvv, bot - top, top);
    }

    __shared__ float lds[NCHUNK][64];
    lds[wv][lane] = acc;
    __syncthreads();
    if (threadIdx.x < 64 && y < P) {
        float sum = ((lds[0][lane] + lds[1][lane]) + lds[2][lane]) + lds[3][lane];
        out[(b * P + y) * NA + a] = sum / 460.0f;
    }
}

// ---- Fallback (no/undersized workspace): bounds-checked direct sampling ----
__device__ __forceinline__ float samp(const float* __restrict__ img, int iy, int ix) {
    unsigned uy = (unsigned)(iy - PAD);
    unsigned ux = (unsigned)(ix - PAD);
    return (uy < (unsigned)IMG && ux < (unsigned)IMG) ? img[uy * IMG + ux] : 0.0f;
}

__global__ __launch_bounds__(256) void radon_fallback(const float* __restrict__ x,
                                                      float* __restrict__ out) {
    const int wid  = blockIdx.x * 4 + (threadIdx.x >> 6);
    const int lane = threadIdx.x & 63;
    if (wid >= NB * NA * P) return;
    const int y  = wid % P;
    const int ba = wid / P;
    const int a  = ba % NA;
    const int b  = ba / NA;
    const float th = (2.8125f * (float)a) * 0.017453292519943295f;
    float s, c;
    __sincosf(th, &s, &c);
    const float ysy = (2.0f * (float)y + 1.0f) / 460.0f - 1.0f;
    const float* img = x + b * IMG * IMG;
    float acc = 0.0f;
    for (int xx = lane; xx < P; xx += 64) {
        const float xsx = (2.0f * (float)xx + 1.0f) / 460.0f - 1.0f;
        const float gx = c * xsx - s * ysy;
        const float gy = s * xsx + c * ysy;
        const float fix = ((gx + 1.0f) * 460.0f - 1.0f) * 0.5f;
        const float fiy = ((gy + 1.0f) * 460.0f - 1.0f) * 0.5f;
        const float ix0f = floorf(fix);
        const float iy0f = floorf(fiy);
        const float wx = fix - ix0f;
        const float wy = fiy - iy0f;
        const int ix0 = (int)ix0f;
        const int iy0 = (int)iy0f;
        const float v00 = samp(img, iy0,     ix0);
        const float v01 = samp(img, iy0,     ix0 + 1);
        const float v10 = samp(img, iy0 + 1, ix0);
        const float v11 = samp(img, iy0 + 1, ix0 + 1);
        acc += v00 * ((1.0f - wy) * (1.0f - wx))
             + v01 * ((1.0f - wy) * wx)
             + v10 * (wy * (1.0f - wx))
             + v11 * (wy * wx);
    }
    #pragma unroll
    for (int off = 32; off; off >>= 1) acc += __shfl_xor(acc, off);
    if (lane == 0) out[(b * P + y) * NA + a] = acc / 460.0f;
}

extern "C" void kernel_launch(void* const* d_in, const int* in_sizes, int n_in,
                              void* d_out, int out_size, void* d_ws, size_t ws_size,
                              hipStream_t stream) {
    const float* x = (const float*)d_in[0];
    float* out = (float*)d_out;

    const size_t buf_elems = (size_t)NB * E_ * E_;
    const size_t need = 2 * buf_elems * sizeof(float);

    if (ws_size >= need) {
        float* pb  = (float*)d_ws;
        float* pbT = pb + buf_elems;
        const int pad_total  = NB * E_ * E_;
        const int pad_blocks = (pad_total + 255) / 256;
        pad2_kernel<<<pad_blocks, 256, 0, stream>>>(x, pb, pbT);
        dim3 grid((P + 63) / 64, NA, NB);           // (8, 64, 4)
        radon_kernel<<<grid, 256, 0, stream>>>(pb, pbT, out);
    } else {
        const int total_waves = NB * NA * P;
        const int blocks = (total_waves + 3) / 4;
        radon_fallback<<<blocks, 256, 0, stream>>>(x, out);
    }
}

// Round 4
// 68.541 us; speedup vs baseline: 2.4120x; 2.4120x over previous
//
#include <hip/hip_runtime.h>
#include <hip/hip_bf16.h>

// Radon transform: x (4,1,384,384) f32 -> out (4,460,64) f32
// pad = 38, Hp = Wp = 460, N_ANGLES = 64.
//
// R4 structure: one wave = 16 outputs = 4 consecutive y (16-lane groups) x 4
// batches. For a fixed sample position (a,y,xx) all 4 batch images share the
// SAME address -> address/floor/weight math amortized 4x. Within a group the
// 16 lanes take 16 consecutive xx (stride 16) -> compact per-load footprint.
// 4-step shuffle reduce within each 16-lane group (no LDS, no barrier).
// Zero-bordered staged image (border 6px, extent 396^2) in normal + transposed
// layout; per angle pick the layout whose row coordinate steps by min(|c|,|s|).

constexpr int IMG = 384;
constexpr int PAD = 38;
constexpr int P   = 460;   // Hp = Wp
constexpr int NA  = 64;
constexpr int NB  = 4;
constexpr int B_  = 6;               // zero border
constexpr int O_  = PAD - B_;        // 32
constexpr int E_  = IMG + 2 * B_;    // 396

__global__ __launch_bounds__(256) void pad2_kernel(const float* __restrict__ x,
                                                   float* __restrict__ pb,
                                                   float* __restrict__ pbT) {
    int idx = blockIdx.x * 256 + threadIdx.x;
    if (idx >= NB * E_ * E_) return;
    int b  = idx / (E_ * E_);
    int r  = idx - b * (E_ * E_);
    int iy = r / E_;
    int ix = r - iy * E_;
    int py = iy + O_ - PAD;
    int px = ix + O_ - PAD;
    float v = ((unsigned)py < (unsigned)IMG && (unsigned)px < (unsigned)IMG)
                  ? x[(b * IMG + py) * IMG + px] : 0.0f;
    pb[idx] = v;
    pbT[(b * E_ + ix) * E_ + iy] = v;
}

__global__ __launch_bounds__(256) void radon_kernel(const float* __restrict__ pb,
                                                    const float* __restrict__ pbT,
                                                    float* __restrict__ out) {
    const int lane = threadIdx.x & 63;
    const int wv   = threadIdx.x >> 6;       // wave in block
    const int l    = lane & 15;              // lane in group
    const int g    = lane >> 4;              // y-group in wave
    const int a    = blockIdx.y;
    const int y    = blockIdx.x * 16 + wv * 4 + g;

    const float th = (2.8125f * (float)a) * 0.017453292519943295f;
    float s, c;
    __sincosf(th, &s, &c);

    const float yf = (float)(y < P ? y : P - 1);
    const float ys = (2.0f * yf + 1.0f) / 460.0f - 1.0f;
    // fix = c*xx + A ; fiy = s*xx + By (padded-image pixel coords)
    const float A  = fmaf(-s, ys, 1.0f) * 230.0f - 0.5f - 229.5f * c;
    const float By = fmaf( c, ys, 1.0f) * 230.0f - 0.5f - 229.5f * s;

    // xx-interval where the stencil can touch the core ([36,424] conservative;
    // rcp error + floor slack covered by +/-2 and the 6px border). 0*inf NaN
    // cases (a=0, By==36/424) yield empty intervals for all-zero rows: safe.
    const float rc = __builtin_amdgcn_rcpf(c);
    const float rs = __builtin_amdgcn_rcpf(s);
    float t0 = (36.0f - A) * rc, t1 = (424.0f - A) * rc;
    float lo = fmaxf(0.0f,   fminf(t0, t1));
    float hi = fminf(459.0f, fmaxf(t0, t1));
    t0 = (36.0f - By) * rs; t1 = (424.0f - By) * rs;
    lo = fmaxf(lo, fminf(t0, t1));
    hi = fminf(hi, fmaxf(t0, t1));

    int glo = max(0, (int)floorf(lo) - 2);
    glo = min(glo, P);                       // saturate +inf case, avoid wrap
    int ghi = min(P - 1, (int)ceilf(hi) + 2);
    if (y >= P) { glo = 1; ghi = 0; }

    // Layout: row coord v should step slowly with xx -> |cv| = min(|c|,|s|).
    const bool  useT = fabsf(s) > fabsf(c);
    const float cu = useT ? s  : c;
    const float Au = useT ? By : A;
    const float cv = useT ? c  : s;
    const float Av = useT ? A  : By;
    const float* __restrict__ base = useT ? pbT : pb;
    const float* __restrict__ i0 = base;
    const float* __restrict__ i1 = base + 1 * E_ * E_;
    const float* __restrict__ i2 = base + 2 * E_ * E_;
    const float* __restrict__ i3 = base + 3 * E_ * E_;

    float acc0 = 0.0f, acc1 = 0.0f, acc2 = 0.0f, acc3 = 0.0f;
    float xxf = (float)(glo + l);
    for (int xx = glo + l; xx <= ghi; xx += 16, xxf += 16.0f) {
        const float u   = fmaf(cu, xxf, Au);
        const float v   = fmaf(cv, xxf, Av);
        const float u0f = floorf(u);
        const float v0f = floorf(v);
        const float wu  = u - u0f;
        const float wvv = v - v0f;
        const int idx = (int)fmaf(v0f, (float)E_, u0f) - (O_ * E_ + O_);

        {
            const float* p = i0 + idx;
            const float p00 = p[0], p01 = p[1], p10 = p[E_], p11 = p[E_ + 1];
            const float top = fmaf(wu, p01 - p00, p00);
            const float bot = fmaf(wu, p11 - p10, p10);
            acc0 += fmaf(wvv, bot - top, top);
        }
        {
            const float* p = i1 + idx;
            const float p00 = p[0], p01 = p[1], p10 = p[E_], p11 = p[E_ + 1];
            const float top = fmaf(wu, p01 - p00, p00);
            const float bot = fmaf(wu, p11 - p10, p10);
            acc1 += fmaf(wvv, bot - top, top);
        }
        {
            const float* p = i2 + idx;
            const float p00 = p[0], p01 = p[1], p10 = p[E_], p11 = p[E_ + 1];
            const float top = fmaf(wu, p01 - p00, p00);
            const float bot = fmaf(wu, p11 - p10, p10);
            acc2 += fmaf(wvv, bot - top, top);
        }
        {
            const float* p = i3 + idx;
            const float p00 = p[0], p01 = p[1], p10 = p[E_], p11 = p[E_ + 1];
            const float top = fmaf(wu, p01 - p00, p00);
            const float bot = fmaf(wu, p11 - p10, p10);
            acc3 += fmaf(wvv, bot - top, top);
        }
    }

    // 4-step butterfly within each 16-lane group; 4 independent chains (ILP)
    #pragma unroll
    for (int m = 1; m <= 8; m <<= 1) {
        acc0 += __shfl_xor(acc0, m);
        acc1 += __shfl_xor(acc1, m);
        acc2 += __shfl_xor(acc2, m);
        acc3 += __shfl_xor(acc3, m);
    }

    if (l == 0 && y < P) {
        out[(0 * P + y) * NA + a] = acc0 / 460.0f;
        out[(1 * P + y) * NA + a] = acc1 / 460.0f;
        out[(2 * P + y) * NA + a] = acc2 / 460.0f;
        out[(3 * P + y) * NA + a] = acc3 / 460.0f;
    }
}

// ---- Fallback (no/undersized workspace): bounds-checked direct sampling ----
__device__ __forceinline__ float samp(const float* __restrict__ img, int iy, int ix) {
    unsigned uy = (unsigned)(iy - PAD);
    unsigned ux = (unsigned)(ix - PAD);
    return (uy < (unsigned)IMG && ux < (unsigned)IMG) ? img[uy * IMG + ux] : 0.0f;
}

__global__ __launch_bounds__(256) void radon_fallback(const float* __restrict__ x,
                                                      float* __restrict__ out) {
    const int wid  = blockIdx.x * 4 + (threadIdx.x >> 6);
    const int lane = threadIdx.x & 63;
    if (wid >= NB * NA * P) return;
    const int y  = wid % P;
    const int ba = wid / P;
    const int a  = ba % NA;
    const int b  = ba / NA;
    const float th = (2.8125f * (float)a) * 0.017453292519943295f;
    float s, c;
    __sincosf(th, &s, &c);
    const float ysy = (2.0f * (float)y + 1.0f) / 460.0f - 1.0f;
    const float* img = x + b * IMG * IMG;
    float acc = 0.0f;
    for (int xx = lane; xx < P; xx += 64) {
        const float xsx = (2.0f * (float)xx + 1.0f) / 460.0f - 1.0f;
        const float gx = c * xsx - s * ysy;
        const float gy = s * xsx + c * ysy;
        const float fix = ((gx + 1.0f) * 460.0f - 1.0f) * 0.5f;
        const float fiy = ((gy + 1.0f) * 460.0f - 1.0f) * 0.5f;
        const float ix0f = floorf(fix);
        const float iy0f = floorf(fiy);
        const float wx = fix - ix0f;
        const float wy = fiy - iy0f;
        const int ix0 = (int)ix0f;
        const int iy0 = (int)iy0f;
        const float v00 = samp(img, iy0,     ix0);
        const float v01 = samp(img, iy0,     ix0 + 1);
        const float v10 = samp(img, iy0 + 1, ix0);
        const float v11 = samp(img, iy0 + 1, ix0 + 1);
        acc += v00 * ((1.0f - wy) * (1.0f - wx))
             + v01 * ((1.0f - wy) * wx)
             + v10 * (wy * (1.0f - wx))
             + v11 * (wy * wx);
    }
    #pragma unroll
    for (int off = 32; off; off >>= 1) acc += __shfl_xor(acc, off);
    if (lane == 0) out[(b * P + y) * NA + a] = acc / 460.0f;
}

extern "C" void kernel_launch(void* const* d_in, const int* in_sizes, int n_in,
                              void* d_out, int out_size, void* d_ws, size_t ws_size,
                              hipStream_t stream) {
    const float* x = (const float*)d_in[0];
    float* out = (float*)d_out;

    const size_t buf_elems = (size_t)NB * E_ * E_;
    const size_t need = 2 * buf_elems * sizeof(float);

    if (ws_size >= need) {
        float* pb  = (float*)d_ws;
        float* pbT = pb + buf_elems;
        const int pad_total  = NB * E_ * E_;
        const int pad_blocks = (pad_total + 255) / 256;
        pad2_kernel<<<pad_blocks, 256, 0, stream>>>(x, pb, pbT);
        dim3 grid((P + 15) / 16, NA, 1);            // (29, 64) = 1856 blocks
        radon_kernel<<<grid, 256, 0, stream>>>(pb, pbT, out);
    } else {
        const int total_waves = NB * NA * P;
        const int blocks = (total_waves + 3) / 4;
        radon_fallback<<<blocks, 256, 0, stream>>>(x, out);
    }
}